// Round 3
// baseline (123.657 us; speedup 1.0000x reference)
//
#include <hip/hip_runtime.h>

// RPN target generation for MI355X — 2-node pipeline: binned-candidate main -> tiny finalize.
// Outputs (float32, concat): [0,A) rpn_match; [A,5A) rpn_bbox (A x 4); [5A] num_positives.
//
// Calibrated lessons (R2-R16 + this round):
//  * same-address device atomics ~100ns/op serialized per address -> depth O(64) max
//    (SHARDS scaled with block count to hold depth at 64).
//  * cross-block visibility ONLY via kernel boundaries (2 nodes).
//  * no memsets: biased keys beat 0xAA ws poison under atomicMax.
//  * R15: interleaved split -> bank conflicts 6.56M -> 511K.
//  * R15: total-minus-main is constant ~62us across rounds -> harness overhead.
//  * R16: R1 vs R2: doubling TLP + halving chain left dur bit-identical (53.56us)
//    -> throughput-bound on total pair work (VALU+LDS issue), ~110 cyc/pair.
//    Only lever: FEWER PAIRS.
//  * R17: 8x8 spatial bin by gt (y1,x1); anchor scans cells with
//    y1 in [ay1-mh, ay2] x [ax1-mw, ax2] — provable superset of inter>0 pairs
//    (zero-IoU pairs are no-ops: best init 0, argmax-of-zeros = 0, no keys).
//    ~25 cands/anchor vs 256. Argmax = in-loop (max, tie-min-g) select since
//    candidate order is nondeterministic; key drain = second candidate pass.
//
// ws layout: [0, G*64*8) gkeyS | [+nb*4) pcount | [+nb*4) fvmin

#define GMAX 256
#define SHARDS 64
#define KBIAS 0xC0000001u   // real key top-words >= 0xC0000002; 0xAAAAAAAA poison loses
#define AIMASK 0x3FFFFu     // 18-bit anchor index field (A <= 2^18 guarded on host)

// Faithful to the reference, including the intentional size "bug":
// gt_size = y2 + y1 (not y2 - y1); centre = 0.5 * (y1 + y2).
__device__ __forceinline__ float4 compute_deltas(float4 ab, float4 gb,
                                                 const float* __restrict__ sd) {
    float sy_g = gb.z + gb.x;   // box = (y1, x1, y2, x2) in (x,y,z,w)
    float sx_g = gb.w + gb.y;
    float sy_a = ab.z + ab.x;
    float sx_a = ab.w + ab.y;
    float4 d;
    d.x = (0.5f * (sy_g - sy_a) / sy_a) / sd[0];
    d.y = (0.5f * (sx_g - sx_a) / sx_a) / sd[1];
    d.z = logf(sy_g / sy_a) / sd[2];
    d.w = logf(sx_g / sx_a) / sd[3];
    return d;
}

// Single IoU formula used by every site. fp contract OFF so recomputation is
// bitwise identical everywhere (argmax tie-break + key drain depend on it).
__device__ __forceinline__ float iou_from(float4 ab, float a_area, float4 gb,
                                          float ga, float& inter) {
#pragma clang fp contract(off)
    float y1 = fmaxf(ab.x, gb.x);
    float x1 = fmaxf(ab.y, gb.y);
    float y2 = fminf(ab.z, gb.z);
    float x2 = fminf(ab.w, gb.w);
    inter = fmaxf(y2 - y1, 0.f) * fmaxf(x2 - x1, 0.f);
    return inter * __builtin_amdgcn_rcpf((a_area + ga) - inter);
}

// Used only by the monolithic fallback kernel (kept verbatim from prior rounds).
__device__ __forceinline__ float iou_of(float4 ab, float a_area, float4 gb) {
    float y1 = fmaxf(ab.x, gb.x);
    float x1 = fmaxf(ab.y, gb.y);
    float y2 = fminf(ab.z, gb.z);
    float x2 = fminf(ab.w, gb.w);
    float inter = fmaxf(y2 - y1, 0.f) * fmaxf(x2 - x1, 0.f);
    float garea = (gb.z - gb.x) * (gb.w - gb.y);
    float uni = (a_area + garea) - inter;
    return inter * __builtin_amdgcn_rcpf(uni);
}

// ---------- kernel 1: 4 threads/anchor, 8x8 binned candidate scan ----------
__global__ __launch_bounds__(256, 8) void rpn_main7(
    const float4* __restrict__ anchors,       // [A]
    const int* __restrict__ valid,            // [A] jnp bool as int32
    const int* __restrict__ cls,              // [G]
    const float4* __restrict__ gt,            // [G]
    const float* __restrict__ stdev,          // [4]
    float* __restrict__ out,                  // [5A+1]
    unsigned long long* __restrict__ gkeyS,   // [G*SHARDS] biased keys, poison-ok
    int* __restrict__ pcount,                 // [nb] plain stores
    int* __restrict__ fvmin,                  // [nb] plain stores (min valid ai, else INT_MAX)
    int A, int G)
{
    __shared__ float4 s_gt[GMAX];
    __shared__ float s_area[GMAX];
    __shared__ float s_crowdf[GMAX];
    __shared__ unsigned long long s_key[GMAX];
    __shared__ unsigned short s_cellgt[GMAX];  // gt indices grouped by cell
    __shared__ int s_cell[64];                 // start | cnt<<16
    __shared__ int s_cellcnt[64];
    __shared__ int s_cur[64];
    __shared__ int s_mhi, s_mwi;               // max gt h/w (float bits, >=0)
    __shared__ int s_anycrowd, s_cnt, s_fv;

    const int tid = threadIdx.x;
    const float inv = 0.0078125f;              // 1/128, exact
    if (tid == 0) { s_anycrowd = 0; s_cnt = 0; s_fv = 0x7FFFFFFF; s_mhi = 0; s_mwi = 0; }
    if (tid < 64) s_cellcnt[tid] = 0;
    s_key[tid] = 0ULL;

    float gh = 0.f, gw = 0.f;
    int mycell = 0;
    if (tid < G) {
        float4 b = gt[tid];
        s_gt[tid] = b;
        s_area[tid] = (b.z - b.x) * (b.w - b.y);
        int c = cls[tid];
        s_crowdf[tid] = (c < 0) ? 1.0f : 0.0f;
        if (c < 0) s_anycrowd = 1;             // benign race, same value
        gh = fmaxf(b.z - b.x, 0.f);
        gw = fmaxf(b.w - b.y, 0.f);
        int rr = max(0, min(7, (int)(b.x * inv)));   // trunc==floor for >=0; neg -> 0
        int cc = max(0, min(7, (int)(b.y * inv)));
        mycell = (rr << 3) + cc;
    }
    // per-wave max-reduce of gt h/w
    #pragma unroll
    for (int off = 32; off >= 1; off >>= 1) {
        gh = fmaxf(gh, __shfl_xor(gh, off));
        gw = fmaxf(gw, __shfl_xor(gw, off));
    }
    __syncthreads();                           // counts zeroed
    if (tid < G) atomicAdd(&s_cellcnt[mycell], 1);
    if ((tid & 63) == 0) {
        atomicMax(&s_mhi, __float_as_int(gh)); // positive floats monotone as int
        atomicMax(&s_mwi, __float_as_int(gw));
    }
    __syncthreads();
    if (tid < 64) {                            // wave 0: 64-wide inclusive scan
        int v0 = s_cellcnt[tid];
        int incl = v0;
        #pragma unroll
        for (int off = 1; off < 64; off <<= 1) {
            int n = __shfl_up(incl, off);
            if (tid >= off) incl += n;
        }
        s_cell[tid] = (incl - v0) | (v0 << 16);
        s_cur[tid]  = incl - v0;
    }
    __syncthreads();
    if (tid < G) {
        int slot = atomicAdd(&s_cur[mycell], 1);
        s_cellgt[slot] = (unsigned short)tid;
    }
    __syncthreads();

    const int any_crowd = s_anycrowd;
    const float mh = __int_as_float(s_mhi);
    const float mw = __int_as_float(s_mwi);

    // lane quad (4a..4a+3) = anchor a; lane h takes candidates k = h, h+4, ...
    const int a  = tid >> 2;
    const int h  = tid & 3;
    const int ai = blockIdx.x * 64 + a;
    const bool ir = (ai < A);
    float4 ab = ir ? anchors[ai] : make_float4(0.f, 0.f, 1.f, 1.f);
    const bool v = ir && (valid[ai] != 0);
    const float a_area = (ab.z - ab.x) * (ab.w - ab.y);

    float best = 0.0f;
    float cm = 0.0f;
    int bg_final = 0;

    if (any_crowd == 0) {
        // ---- binned fast path. Candidate cells: gt y1 in [ay1-mh, ay2],
        // x1 in [ax1-mw, ax2] (clamped) — superset of all inter>0 pairs. ----
        float t0 = (ab.x - mh) * inv;
        const int r0 = (t0 <= 0.f) ? 0 : min(7, (int)t0);
        const int r1 = min(7, max(0, (int)(ab.z * inv)));
        float u0 = (ab.y - mw) * inv;
        const int c0 = (u0 <= 0.f) ? 0 : min(7, (int)u0);
        const int c1 = min(7, max(0, (int)(ab.w * inv)));

        float bb = 0.f; int bg = 0;            // all-zero row -> argmax 0 (matches ref)
        for (int r = r0; r <= r1; ++r) {
            for (int c = c0; c <= c1; ++c) {
                const unsigned sc = (unsigned)s_cell[(r << 3) + c];
                const int start = (int)(sc & 0xFFFFu);
                const int cnt   = (int)(sc >> 16);
                for (int k = h; k < cnt; k += 4) {
                    const int g = (int)s_cellgt[start + k];
                    float it;
                    float iou = iou_from(ab, a_area, s_gt[g], s_area[g], it);
                    // candidate order is nondeterministic -> explicit tie-min-g
                    if (iou > bb) { bb = iou; bg = g; }
                    else if (iou == bb && g < bg) bg = g;
                }
            }
        }
        // symmetric quad merge with first-index tie-break
        #pragma unroll
        for (int off = 1; off <= 2; off <<= 1) {
            float ob = __shfl_xor(bb, off);
            int  obg = __shfl_xor(bg, off);
            if (ob > bb || (ob == bb && obg < bg)) { bb = ob; bg = obg; }
        }
        best = bb; bg_final = bg;

        // ---- pass 2: column-key drain over the same candidate subset ----
        if (v) {
            if (h == 0) atomicMin(&s_fv, ai);
            const unsigned long long lo =
                (((unsigned long long)((~(unsigned)ai) & AIMASK)) << 8) |
                (unsigned long long)((unsigned)bg_final & 0xFFu);
            for (int r = r0; r <= r1; ++r) {
                for (int c = c0; c <= c1; ++c) {
                    const unsigned sc = (unsigned)s_cell[(r << 3) + c];
                    const int start = (int)(sc & 0xFFFFu);
                    const int cnt   = (int)(sc >> 16);
                    for (int k = h; k < cnt; k += 4) {
                        const int g = (int)s_cellgt[start + k];
                        float it;
                        float iou = iou_from(ab, a_area, s_gt[g], s_area[g], it);
                        if (it > 0.f)
                            atomicMax(&s_key[g],
                                (((unsigned long long)(__float_as_uint(iou) + KBIAS)) << 32) | lo);
                    }
                }
            }
        }
    } else {
        // ---- general path: crowd (dense, contiguous quarters — correctness-only) ----
        const int Gq = (G + 3) >> 2;
        const int g0 = h * Gq;
        const int gn = max(0, min(G - g0, Gq));
        unsigned long long mm = 0ULL;
        float bestg = -2.0f;
        int bg = min(g0, G - 1);
        for (int gg = 0; gg < gn; ++gg) {
            const int g = g0 + gg;
            float it;
            float iou = iou_from(ab, a_area, s_gt[g], s_area[g], it);
            float cf = s_crowdf[g];
            float eff = (cf != 0.0f) ? -1.0f : iou;
            if (eff > bestg) { bestg = eff; bg = g; }
            cm = fmaxf(cm, iou * cf);
            if (cf == 0.0f && iou > 0.0f) mm |= (1ULL << gg);
        }
        #pragma unroll
        for (int off = 1; off <= 2; off <<= 1) {
            float ob  = __shfl_xor(bestg, off);
            int   obg = __shfl_xor(bg, off);
            float ocm = __shfl_xor(cm, off);
            if (ob > bestg || (ob == bestg && obg < bg)) { bestg = ob; bg = obg; }
            cm = fmaxf(cm, ocm);
        }
        best = bestg; bg_final = bg;

        if (v) {
            if (h == 0) atomicMin(&s_fv, ai);
            const unsigned long long lo =
                (((unsigned long long)((~(unsigned)ai) & AIMASK)) << 8) |
                (unsigned long long)((unsigned)bg_final & 0xFFu);
            unsigned long long m = mm;
            while (m != 0ULL) {
                int j = __builtin_ctzll(m); m &= (m - 1ULL);
                const int g = g0 + j;
                float it;
                float iou = iou_from(ab, a_area, s_gt[g], s_area[g], it);
                atomicMax(&s_key[g],
                    (((unsigned long long)(__float_as_uint(iou) + KBIAS)) << 32) | lo);
            }
        }
    }

    bool no_crowd = any_crowd ? (cm < 0.001f) : true;
    bool pos = (best >= 0.7f);
    bool neg = (best < 0.3f) && no_crowd && !pos;
    bool posv = (h == 0) && pos && v;

    if (ir && h == 0) {
        out[ai] = v ? (pos ? 1.0f : (neg ? -1.0f : 0.0f)) : 0.0f;
        float4 d = make_float4(0.f, 0.f, 0.f, 0.f);
        if (pos && v) d = compute_deltas(ab, s_gt[bg_final], stdev);
        ((float4*)(out + A))[ai] = d;
    }

    unsigned long long bal = __ballot((int)posv);
    if ((tid & 63) == 0) atomicAdd(&s_cnt, (int)__popcll(bal));   // LDS only
    __syncthreads();

    // sharded global merge: 4092/64 = 64-deep per address (calibrated ok)
    if (tid < G && s_key[tid] != 0ULL)
        atomicMax(&gkeyS[(size_t)tid * SHARDS + (blockIdx.x & (SHARDS - 1))],
                  s_key[tid]);
    if (tid == 0) { pcount[blockIdx.x] = s_cnt; fvmin[blockIdx.x] = s_fv; }
}

// ---------- kernel 2: single-block finalize, register shard-reduce ----------
__global__ __launch_bounds__(1024) void rpn_finalize3(
    const float4* __restrict__ anchors,
    const int* __restrict__ cls,
    const float4* __restrict__ gt,
    const float* __restrict__ stdev,
    float* __restrict__ out,
    const unsigned long long* __restrict__ gkeyS,
    const int* __restrict__ pcount,
    const int* __restrict__ fvmin,
    int nb, int A, int G)
{
    __shared__ float4 s_gt[GMAX];
    __shared__ float s_area[GMAX];
    __shared__ float s_crowdf[GMAX];
    __shared__ int s_tot, s_fvr, s_flip;

    const int tid = threadIdx.x;
    if (tid == 0) { s_tot = 0; s_fvr = 0x7FFFFFFF; s_flip = 0; }
    if (tid < G) {
        float4 b = gt[tid];
        s_gt[tid] = b;
        s_area[tid] = (b.z - b.x) * (b.w - b.y);
        s_crowdf[tid] = (cls[tid] < 0) ? 1.0f : 0.0f;
    }
    __syncthreads();

    // thread g reduces its own SHARDS shards in registers: independent 16B
    // loads (full MLP), zero LDS atomics, line-granular reads.
    unsigned long long key = 0ULL;
    if (tid < G) {
        const unsigned long long* p = gkeyS + (size_t)tid * SHARDS;
        #pragma unroll
        for (int s = 0; s < SHARDS; s += 2) {
            ulonglong2 kv = *reinterpret_cast<const ulonglong2*>(p + s);
            unsigned long long k = (kv.x > kv.y) ? kv.x : kv.y;
            key = (k > key) ? k : key;
        }
    }
    // waves 4..15: pcount sum + fvmin min via shfl trees (12 LDS atomics total)
    if (tid >= 256) {
        int acc = 0, fv = 0x7FFFFFFF;
        for (int i = tid - 256; i < nb; i += 768) {
            acc += pcount[i];
            fv = min(fv, fvmin[i]);
        }
        #pragma unroll
        for (int off = 32; off >= 1; off >>= 1) {
            acc += __shfl_xor(acc, off);
            fv = min(fv, __shfl_xor(fv, off));
        }
        if ((tid & 63) == 0) { atomicAdd(&s_tot, acc); atomicMin(&s_fvr, fv); }
    }
    __syncthreads();   // s_tot/s_fvr final

    bool flipped = false;
    if (tid < G && s_crowdf[tid] == 0.0f) {    // scatter value is False for crowd gts
        const bool has = ((unsigned)(key >> 32) >= (KBIAS + 1u));  // poison/empty -> none
        int w = -1, bg = -1;
        if (has) {
            w  = (int)((~((unsigned)key >> 8)) & AIMASK);
            bg = (int)((unsigned)key & 0xFFu);
        } else if (s_fvr != 0x7FFFFFFF) {
            // no valid anchor overlapped this gt: column argmax = first valid anchor
            w = s_fvr;
        }
        if (w >= 0) {
            float old = atomicExch(out + w, 1.0f);   // <=256 ops, mostly distinct addrs
            if (old != 1.0f) {
                if (bg < 0) {
                    // rare fallback: recompute w's own crowd-masked argmax
                    float4 ab = anchors[w];
                    float aa = (ab.z - ab.x) * (ab.w - ab.y);
                    float bb = -2.0f; bg = 0;
                    for (int g = 0; g < G; ++g) {
                        float it;
                        float iou = iou_from(ab, aa, s_gt[g], s_area[g], it);
                        float eff = (s_crowdf[g] != 0.0f) ? -1.0f : iou;
                        if (eff > bb) { bb = eff; bg = g; }
                    }
                }
                ((float4*)(out + A))[w] = compute_deltas(anchors[w], s_gt[bg], stdev);
                flipped = true;
            }
        }
    }
    unsigned long long fb = __ballot((int)flipped);
    if (tid < 256 && (tid & 63) == 0) atomicAdd(&s_flip, (int)__popcll(fb));
    __syncthreads();
    if (tid == 0) out[(size_t)5 * A] = (float)(s_tot + s_flip);
}

// ---------------- fallback: monolithic kernel (used only if ws too small / A>2^18) ------
__global__ __launch_bounds__(256) void rpn_fused(
    const float4* __restrict__ anchors, const int* __restrict__ valid,
    const int* __restrict__ cls, const float4* __restrict__ gt,
    const float* __restrict__ stdev, float* __restrict__ out,
    unsigned long long* __restrict__ gkey, unsigned* __restrict__ done,
    int* __restrict__ cnt, int A, int G)
{
    __shared__ float4 s_gt[GMAX];
    __shared__ float s_crowdf[GMAX];
    __shared__ unsigned long long s_key[GMAX];
    __shared__ int s_anycrowd; __shared__ int s_cnt; __shared__ int s_islast;

    const int tid = threadIdx.x;
    if (tid == 0) { s_anycrowd = 0; s_cnt = 0; }
    if (tid < G) {
        s_gt[tid] = gt[tid];
        int c = cls[tid];
        s_crowdf[tid] = (c < 0) ? 1.0f : 0.0f;
        if (c < 0) s_anycrowd = 1;
        s_key[tid] = 0ULL;
    }
    __syncthreads();
    const int any_crowd = s_anycrowd;
    const int ai = blockIdx.x * 256 + tid;
    const bool in_range = (ai < A);
    float4 ab = in_range ? anchors[ai] : make_float4(0.f, 0.f, 1.f, 1.f);
    const bool v = in_range && (valid[ai] != 0);
    const float a_area = (ab.z - ab.x) * (ab.w - ab.y);
    const unsigned lokey = ~(unsigned)ai;

    float best = any_crowd ? -2.0f : -1.0f;
    int bg = 0; float crowd_max = 0.0f;
    unsigned long long ovmask[4];
    #pragma unroll
    for (int w = 0; w < 4; ++w) {
        unsigned long long m = 0ULL;
        #pragma unroll 4
        for (int j = 0; j < 64; ++j) {
            int g = (w << 6) + j;
            if (g >= G) break;
            float iou = iou_of(ab, a_area, s_gt[g]);
            float cf = s_crowdf[g];
            float eff = (any_crowd && cf != 0.0f) ? -1.0f : iou;
            if (eff > best) { best = eff; bg = g; }
            if (any_crowd) crowd_max = fmaxf(crowd_max, iou * cf);
            if (v && (cf == 0.0f) && iou > 0.0f) m |= (1ULL << j);
        }
        ovmask[w] = m;
    }
    #pragma unroll
    for (int w = 0; w < 4; ++w) {
        unsigned long long m = ovmask[w];
        while (m != 0ULL) {
            int j = __builtin_ctzll(m); m &= (m - 1ULL);
            int g = (w << 6) + j;
            float iou = iou_of(ab, a_area, s_gt[g]);
            atomicMax(&s_key[g],
                (((unsigned long long)(__float_as_uint(iou) + 1u)) << 32) | lokey);
        }
    }
    bool no_crowd = any_crowd ? (crowd_max < 0.001f) : true;
    bool pos = (best >= 0.7f);
    bool neg = (best < 0.3f) && no_crowd && !pos;
    unsigned long long pv = __ballot((int)(in_range && pos && v));
    if ((tid & 63) == 0) atomicAdd(&s_cnt, (int)__popcll(pv));
    if (in_range) {
        out[ai] = v ? (pos ? 1.0f : (neg ? -1.0f : 0.0f)) : 0.0f;
        float4 d = make_float4(0.f, 0.f, 0.f, 0.f);
        if (pos && v) d = compute_deltas(ab, s_gt[bg], stdev);
        ((float4*)(out + A))[ai] = d;
    }
    __syncthreads();
    if (tid < G && s_key[tid] != 0ULL) atomicMax(&gkey[tid], s_key[tid]);
    if (tid == 0 && s_cnt > 0) atomicAdd(cnt, s_cnt);
    __threadfence();
    if (tid == 0) {
        unsigned prev = atomicAdd(done, 1u);
        s_islast = (prev == gridDim.x - 1);
        s_cnt = 0;
    }
    __syncthreads();
    if (!s_islast) return;
    __threadfence();
    if (tid < G && s_crowdf[tid] == 0.0f) {
        unsigned long long key = gkey[tid];
        int w;
        if (key != 0ULL) w = (int)(~(unsigned)(key & 0xFFFFFFFFull));
        else { w = 0; for (int i = 0; i < A; ++i) { if (valid[i] != 0) { w = i; break; } } }
        if (valid[w] != 0) {
            float old = atomicExch(out + w, 1.0f);
            if (old != 1.0f) {
                float4 ab2 = anchors[w];
                float a2 = (ab2.z - ab2.x) * (ab2.w - ab2.y);
                float b2 = -2.0f; int g2 = 0;
                for (int g = 0; g < G; ++g) {
                    float iou = iou_of(ab2, a2, s_gt[g]);
                    float eff = (s_crowdf[g] != 0.0f) ? -1.0f : iou;
                    if (eff > b2) { b2 = eff; g2 = g; }
                }
                ((float4*)(out + A))[w] = compute_deltas(ab2, s_gt[g2], stdev);
                atomicAdd(&s_cnt, 1);
            }
        }
    }
    __syncthreads();
    if (tid == 0) out[(size_t)5 * A] = (float)(*cnt + s_cnt);
}

extern "C" void kernel_launch(void* const* d_in, const int* in_sizes, int n_in,
                              void* d_out, int out_size, void* d_ws, size_t ws_size,
                              hipStream_t stream) {
    const float4* anchors = (const float4*)d_in[0];
    const int* valid      = (const int*)d_in[1];   // jnp bool -> int32 per element
    const int* cls        = (const int*)d_in[2];
    const float4* gtb     = (const float4*)d_in[3];
    const float* stdev    = (const float*)d_in[4];
    float* out            = (float*)d_out;

    const int A = in_sizes[0] / 4;
    const int G = in_sizes[2];                     // 256
    const int nb4 = (A + 63) / 64;                 // 4092 blocks (64 anchors/block)

    const size_t shard_bytes = (size_t)G * SHARDS * 8;
    const size_t pcnt_bytes  = (size_t)nb4 * 4;
    const size_t fv_bytes    = (size_t)nb4 * 4;
    const size_t needed = shard_bytes + pcnt_bytes + fv_bytes;

    if (ws_size >= needed && G <= GMAX && A <= (1 << 18)) {
        char* p = (char*)d_ws;
        unsigned long long* gkeyS = (unsigned long long*)p;          p += shard_bytes;
        int* pcount               = (int*)p;                         p += pcnt_bytes;
        int* fvmin                = (int*)p;

        rpn_main7<<<nb4, 256, 0, stream>>>(anchors, valid, cls, gtb, stdev, out,
                                           gkeyS, pcount, fvmin, A, G);
        rpn_finalize3<<<1, 1024, 0, stream>>>(anchors, cls, gtb, stdev, out,
                                              gkeyS, pcount, fvmin, nb4, A, G);
    } else {
        const int nb = (A + 255) / 256;
        unsigned long long* gkey = (unsigned long long*)d_ws;
        unsigned* done = (unsigned*)((char*)d_ws + 2048);
        int* cnt       = (int*)((char*)d_ws + 2052);
        hipMemsetAsync(d_ws, 0, 2056, stream);
        rpn_fused<<<nb, 256, 0, stream>>>(anchors, valid, cls, gtb, stdev, out,
                                          gkey, done, cnt, A, G);
    }
}

// Round 4
// 121.148 us; speedup vs baseline: 1.0207x; 1.0207x over previous
//
#include <hip/hip_runtime.h>

// RPN target generation for MI355X — 2-node pipeline: register-blocked main -> tiny finalize.
// Outputs (float32, concat): [0,A) rpn_match; [A,5A) rpn_bbox (A x 4); [5A] num_positives.
//
// Calibrated lessons (R2-R17 + this round):
//  * same-address device atomics ~100ns/op serialized per address -> depth O(64) max
//    (SHARDS holds per-address depth at <=64).
//  * cross-block visibility ONLY via kernel boundaries (2 nodes).
//  * no memsets: biased keys beat 0xAA ws poison under atomicMax.
//  * R15: total-minus-main is constant ~62us across rounds -> harness overhead.
//  * R16: R1==R2 bit-identical dur under 2x TLP / half chain -> not latency-bound.
//  * R17: 8x8 binning cut pairs ~7x but dur unchanged (VALUBusy 88->68, conflicts 5x)
//    -> the invariant is LDS-ISSUE: 2 ds_read per pair-iter per wave; (waves x iters)
//    was constant across R1/R2/R3. VALU floor is only ~16us.
//  * R18: register-block 4 anchors/thread -> each gt ds_read feeds 4 IoUs (LDS /4),
//    wave count /4, VALU becomes dominant pipe. Argmax kept out of hot loop
//    (v_max + equality re-scan, fp-contract(off) helper = bitwise identical).
//    No runtime-indexed arrays (rule: dynamic idx -> scratch); sel4 is branchless.
//
// ws layout: [0, G*64*8) gkeyS | [+nb*4) pcount | [+nb*4) fvmin

#define GMAX 256
#define SHARDS 64
#define KBIAS 0xC0000001u   // real key top-words >= 0xC0000002; 0xAAAAAAAA poison loses
#define AIMASK 0x3FFFFu     // 18-bit anchor index field (A <= 2^18 guarded on host)

// Faithful to the reference, including the intentional size "bug":
// gt_size = y2 + y1 (not y2 - y1); centre = 0.5 * (y1 + y2).
__device__ __forceinline__ float4 compute_deltas(float4 ab, float4 gb,
                                                 const float* __restrict__ sd) {
    float sy_g = gb.z + gb.x;   // box = (y1, x1, y2, x2) in (x,y,z,w)
    float sx_g = gb.w + gb.y;
    float sy_a = ab.z + ab.x;
    float sx_a = ab.w + ab.y;
    float4 d;
    d.x = (0.5f * (sy_g - sy_a) / sy_a) / sd[0];
    d.y = (0.5f * (sx_g - sx_a) / sx_a) / sd[1];
    d.z = logf(sy_g / sy_a) / sd[2];
    d.w = logf(sx_g / sx_a) / sd[3];
    return d;
}

// Single IoU formula used by every site. fp contract OFF so recomputation is
// bitwise identical everywhere (argmax equality re-scan + key drain depend on it).
__device__ __forceinline__ float iou_from(float4 ab, float a_area, float4 gb,
                                          float ga, float& inter) {
#pragma clang fp contract(off)
    float y1 = fmaxf(ab.x, gb.x);
    float x1 = fmaxf(ab.y, gb.y);
    float y2 = fminf(ab.z, gb.z);
    float x2 = fminf(ab.w, gb.w);
    inter = fmaxf(y2 - y1, 0.f) * fmaxf(x2 - x1, 0.f);
    return inter * __builtin_amdgcn_rcpf((a_area + ga) - inter);
}

// Used only by the monolithic fallback kernel (kept verbatim from prior rounds).
__device__ __forceinline__ float iou_of(float4 ab, float a_area, float4 gb) {
    float y1 = fmaxf(ab.x, gb.x);
    float x1 = fmaxf(ab.y, gb.y);
    float y2 = fminf(ab.z, gb.z);
    float x2 = fminf(ab.w, gb.w);
    float inter = fmaxf(y2 - y1, 0.f) * fmaxf(x2 - x1, 0.f);
    float garea = (gb.z - gb.x) * (gb.w - gb.y);
    float uni = (a_area + garea) - inter;
    return inter * __builtin_amdgcn_rcpf(uni);
}

// branchless 4-way select (avoids runtime-indexed arrays -> scratch)
__device__ __forceinline__ float sel4f(float a0, float a1, float a2, float a3, int h) {
    float lo = (h & 1) ? a1 : a0;
    float hi = (h & 1) ? a3 : a2;
    return (h & 2) ? hi : lo;
}
__device__ __forceinline__ int sel4i(int a0, int a1, int a2, int a3, int h) {
    int lo = (h & 1) ? a1 : a0;
    int hi = (h & 1) ? a3 : a2;
    return (h & 2) ? hi : lo;
}
__device__ __forceinline__ float4 sel4f4(float4 a0, float4 a1, float4 a2, float4 a3, int h) {
    float4 r;
    r.x = sel4f(a0.x, a1.x, a2.x, a3.x, h);
    r.y = sel4f(a0.y, a1.y, a2.y, a3.y, h);
    r.z = sel4f(a0.z, a1.z, a2.z, a3.z, h);
    r.w = sel4f(a0.w, a1.w, a2.w, a3.w, h);
    return r;
}

// ---------- kernel 1: 4 anchors/thread, quad splits G stride-4 ----------
__global__ __launch_bounds__(256, 4) void rpn_main8(
    const float4* __restrict__ anchors,       // [A]
    const int* __restrict__ valid,            // [A] jnp bool as int32
    const int* __restrict__ cls,              // [G]
    const float4* __restrict__ gt,            // [G]
    const float* __restrict__ stdev,          // [4]
    float* __restrict__ out,                  // [5A+1]
    unsigned long long* __restrict__ gkeyS,   // [G*SHARDS] biased keys, poison-ok
    int* __restrict__ pcount,                 // [nb] plain stores
    int* __restrict__ fvmin,                  // [nb] plain stores (min valid ai, else INT_MAX)
    int A, int G)
{
    __shared__ float4 s_gt[GMAX];
    __shared__ float s_area[GMAX];
    __shared__ float s_crowdf[GMAX];
    __shared__ unsigned long long s_key[GMAX];
    __shared__ int s_anycrowd, s_cnt, s_fv;

    const int tid = threadIdx.x;
    if (tid == 0) { s_anycrowd = 0; s_cnt = 0; s_fv = 0x7FFFFFFF; }
    s_key[tid] = 0ULL;
    if (tid < G) {
        float4 b = gt[tid];
        s_gt[tid] = b;
        s_area[tid] = (b.z - b.x) * (b.w - b.y);
        int c = cls[tid];
        s_crowdf[tid] = (c < 0) ? 1.0f : 0.0f;
        if (c < 0) s_anycrowd = 1;            // benign race, same value
    }
    __syncthreads();
    const int any_crowd = s_anycrowd;

    const int q = tid >> 2;                   // quad id 0..63
    const int h = tid & 3;                    // gt-phase within quad
    const int abase = blockIdx.x * 256 + (q << 2);
    const int myai  = blockIdx.x * 256 + tid; // the anchor this lane OWNS for output
    const bool myir = (myai < A);

    bool posv = false, vmy = false;

    if (!any_crowd && G == GMAX) {
        // ---- fast path: 4 anchors in registers; lane h scans g = 4j+h ----
        float4 ab[4]; float aar[4]; int vld[4];
        #pragma unroll
        for (int k = 0; k < 4; ++k) {
            const int ak = abase + k;
            const bool irk = (ak < A);
            ab[k]  = irk ? anchors[ak] : make_float4(0.f, 0.f, 1.f, 1.f);
            vld[k] = irk ? valid[ak] : 0;
            aar[k] = (ab[k].z - ab[k].x) * (ab[k].w - ab[k].y);
        }

        float best[4] = {0.f, 0.f, 0.f, 0.f};
        unsigned long long msk[4] = {0ULL, 0ULL, 0ULL, 0ULL};
        const float4* gp  = &s_gt[h];         // wave reads one 64B span per j: conflict-free
        const float*  apb = &s_area[h];
        #pragma unroll 8
        for (int j = 0; j < 64; ++j) {
            float4 gb = gp[j << 2];
            float  ga = apb[j << 2];
            #pragma unroll
            for (int k = 0; k < 4; ++k) {
                float it;
                float iou = iou_from(ab[k], aar[k], gb, ga, it);
                best[k] = fmaxf(best[k], iou);          // no selects in hot loop
                if (it > 0.f) msk[k] |= (1ULL << j);
            }
        }

        // quad-merge max per anchor (all lanes end with all 4 merged maxima)
        float mb[4];
        #pragma unroll
        for (int k = 0; k < 4; ++k) {
            float b = best[k];
            b = fmaxf(b, __shfl_xor(b, 1));
            b = fmaxf(b, __shfl_xor(b, 2));
            mb[k] = b;
        }
        // argmax recovery: per-lane sparse equality re-scan (increasing g), quad-min
        int bgm[4];
        #pragma unroll
        for (int k = 0; k < 4; ++k) {
            int be = 0x7FFFFFFF;
            if (mb[k] > 0.f) {
                unsigned long long m = msk[k];
                while (m != 0ULL) {
                    int j = __builtin_ctzll(m); m &= (m - 1ULL);
                    int g = (j << 2) + h;
                    float it;
                    float iou = iou_from(ab[k], aar[k], s_gt[g], s_area[g], it);
                    if (iou == mb[k]) { be = g; break; }
                }
            }
            be = min(be, __shfl_xor(be, 1));
            be = min(be, __shfl_xor(be, 2));
            bgm[k] = (be == 0x7FFFFFFF) ? 0 : be;   // all-zero row -> argmax 0
        }

        // outputs: lane h owns anchor abase+h == myai (coalesced across wave)
        const float4 abm = sel4f4(ab[0], ab[1], ab[2], ab[3], h);
        const float  mbm = sel4f(mb[0], mb[1], mb[2], mb[3], h);
        const int    bgmy = sel4i(bgm[0], bgm[1], bgm[2], bgm[3], h);
        const int    vm   = sel4i(vld[0], vld[1], vld[2], vld[3], h);
        vmy = myir && (vm != 0);
        bool pos = (mbm >= 0.7f);
        bool neg = (mbm < 0.3f) && !pos;     // no crowd in this path
        posv = pos && vmy;
        if (myir) {
            out[myai] = vmy ? (pos ? 1.0f : (neg ? -1.0f : 0.0f)) : 0.0f;
            float4 d = make_float4(0.f, 0.f, 0.f, 0.f);
            if (pos && vmy) d = compute_deltas(abm, s_gt[bgmy], stdev);
            ((float4*)(out + A))[myai] = d;
        }

        // sparse key drain: this lane's quarter, all 4 anchors
        #pragma unroll
        for (int k = 0; k < 4; ++k) {
            if (vld[k]) {
                const unsigned long long lo =
                    (((unsigned long long)((~(unsigned)(abase + k)) & AIMASK)) << 8) |
                    (unsigned long long)((unsigned)bgm[k] & 0xFFu);
                unsigned long long m = msk[k];
                while (m != 0ULL) {
                    int j = __builtin_ctzll(m); m &= (m - 1ULL);
                    int g = (j << 2) + h;
                    float it;
                    float iou = iou_from(ab[k], aar[k], s_gt[g], s_area[g], it);
                    atomicMax(&s_key[g],
                        (((unsigned long long)(__float_as_uint(iou) + KBIAS)) << 32) | lo);
                }
            }
        }
    } else {
        // ---- general path: crowd / odd G (1 anchor/thread, dense — correctness-only) ----
        float4 ab2 = myir ? anchors[myai] : make_float4(0.f, 0.f, 1.f, 1.f);
        int v2 = myir ? valid[myai] : 0;
        float aa2 = (ab2.z - ab2.x) * (ab2.w - ab2.y);
        float bb = -2.f; int bg = 0; float cmx = 0.f;
        unsigned long long mk[4] = {0ULL, 0ULL, 0ULL, 0ULL};
        #pragma unroll
        for (int w = 0; w < 4; ++w) {
            unsigned long long m = 0ULL;
            for (int j = 0; j < 64; ++j) {
                int g = (w << 6) + j;
                if (g >= G) break;
                float it;
                float iou = iou_from(ab2, aa2, s_gt[g], s_area[g], it);
                float cf = s_crowdf[g];
                float eff = (cf != 0.f) ? -1.f : iou;
                if (eff > bb) { bb = eff; bg = g; }
                cmx = fmaxf(cmx, iou * cf);
                if (cf == 0.f && it > 0.f) m |= (1ULL << j);
            }
            mk[w] = m;
        }
        bool no_crowd = (cmx < 0.001f);
        vmy = myir && (v2 != 0);
        bool pos = (bb >= 0.7f);
        bool neg = (bb < 0.3f) && no_crowd && !pos;
        posv = pos && vmy;
        if (myir) {
            out[myai] = vmy ? (pos ? 1.0f : (neg ? -1.0f : 0.0f)) : 0.0f;
            float4 d = make_float4(0.f, 0.f, 0.f, 0.f);
            if (pos && vmy) d = compute_deltas(ab2, s_gt[bg], stdev);
            ((float4*)(out + A))[myai] = d;
        }
        if (vmy) {
            const unsigned long long lo =
                (((unsigned long long)((~(unsigned)myai) & AIMASK)) << 8) |
                (unsigned long long)((unsigned)bg & 0xFFu);
            #pragma unroll
            for (int w = 0; w < 4; ++w) {
                unsigned long long m = mk[w];
                while (m != 0ULL) {
                    int j = __builtin_ctzll(m); m &= (m - 1ULL);
                    int g = (w << 6) + j;
                    float it;
                    float iou = iou_from(ab2, aa2, s_gt[g], s_area[g], it);
                    atomicMax(&s_key[g],
                        (((unsigned long long)(__float_as_uint(iou) + KBIAS)) << 32) | lo);
                }
            }
        }
    }

    // ---- common epilogue: per-wave count + min-valid, then sharded global merge ----
    unsigned long long bal = __ballot((int)posv);
    if ((tid & 63) == 0) atomicAdd(&s_cnt, (int)__popcll(bal));   // LDS only
    unsigned long long vb = __ballot((int)vmy);                   // anchors consecutive by tid
    if ((tid & 63) == 0 && vb != 0ULL)
        atomicMin(&s_fv, (int)(blockIdx.x * 256 + (tid & ~63) + (int)__builtin_ctzll(vb)));
    __syncthreads();

    // sharded global merge: 1023/64 = ~16-deep per address (calibrated ok)
    if (tid < G && s_key[tid] != 0ULL)
        atomicMax(&gkeyS[(size_t)tid * SHARDS + (blockIdx.x & (SHARDS - 1))],
                  s_key[tid]);
    if (tid == 0) { pcount[blockIdx.x] = s_cnt; fvmin[blockIdx.x] = s_fv; }
}

// ---------- kernel 2: single-block finalize, register shard-reduce ----------
__global__ __launch_bounds__(1024) void rpn_finalize3(
    const float4* __restrict__ anchors,
    const int* __restrict__ cls,
    const float4* __restrict__ gt,
    const float* __restrict__ stdev,
    float* __restrict__ out,
    const unsigned long long* __restrict__ gkeyS,
    const int* __restrict__ pcount,
    const int* __restrict__ fvmin,
    int nb, int A, int G)
{
    __shared__ float4 s_gt[GMAX];
    __shared__ float s_area[GMAX];
    __shared__ float s_crowdf[GMAX];
    __shared__ int s_tot, s_fvr, s_flip;

    const int tid = threadIdx.x;
    if (tid == 0) { s_tot = 0; s_fvr = 0x7FFFFFFF; s_flip = 0; }
    if (tid < G) {
        float4 b = gt[tid];
        s_gt[tid] = b;
        s_area[tid] = (b.z - b.x) * (b.w - b.y);
        s_crowdf[tid] = (cls[tid] < 0) ? 1.0f : 0.0f;
    }
    __syncthreads();

    // thread g reduces its own SHARDS shards in registers: independent 16B
    // loads (full MLP), zero LDS atomics, line-granular reads.
    unsigned long long key = 0ULL;
    if (tid < G) {
        const unsigned long long* p = gkeyS + (size_t)tid * SHARDS;
        #pragma unroll
        for (int s = 0; s < SHARDS; s += 2) {
            ulonglong2 kv = *reinterpret_cast<const ulonglong2*>(p + s);
            unsigned long long k = (kv.x > kv.y) ? kv.x : kv.y;
            key = (k > key) ? k : key;
        }
    }
    // waves 4..15: pcount sum + fvmin min via shfl trees (12 LDS atomics total)
    if (tid >= 256) {
        int acc = 0, fv = 0x7FFFFFFF;
        for (int i = tid - 256; i < nb; i += 768) {
            acc += pcount[i];
            fv = min(fv, fvmin[i]);
        }
        #pragma unroll
        for (int off = 32; off >= 1; off >>= 1) {
            acc += __shfl_xor(acc, off);
            fv = min(fv, __shfl_xor(fv, off));
        }
        if ((tid & 63) == 0) { atomicAdd(&s_tot, acc); atomicMin(&s_fvr, fv); }
    }
    __syncthreads();   // s_tot/s_fvr final

    bool flipped = false;
    if (tid < G && s_crowdf[tid] == 0.0f) {    // scatter value is False for crowd gts
        const bool has = ((unsigned)(key >> 32) >= (KBIAS + 1u));  // poison/empty -> none
        int w = -1, bg = -1;
        if (has) {
            w  = (int)((~((unsigned)key >> 8)) & AIMASK);
            bg = (int)((unsigned)key & 0xFFu);
        } else if (s_fvr != 0x7FFFFFFF) {
            // no valid anchor overlapped this gt: column argmax = first valid anchor
            w = s_fvr;
        }
        if (w >= 0) {
            float old = atomicExch(out + w, 1.0f);   // <=256 ops, mostly distinct addrs
            if (old != 1.0f) {
                if (bg < 0) {
                    // rare fallback: recompute w's own crowd-masked argmax
                    float4 ab = anchors[w];
                    float aa = (ab.z - ab.x) * (ab.w - ab.y);
                    float bb = -2.0f; bg = 0;
                    for (int g = 0; g < G; ++g) {
                        float it;
                        float iou = iou_from(ab, aa, s_gt[g], s_area[g], it);
                        float eff = (s_crowdf[g] != 0.0f) ? -1.0f : iou;
                        if (eff > bb) { bb = eff; bg = g; }
                    }
                }
                ((float4*)(out + A))[w] = compute_deltas(anchors[w], s_gt[bg], stdev);
                flipped = true;
            }
        }
    }
    unsigned long long fb = __ballot((int)flipped);
    if (tid < 256 && (tid & 63) == 0) atomicAdd(&s_flip, (int)__popcll(fb));
    __syncthreads();
    if (tid == 0) out[(size_t)5 * A] = (float)(s_tot + s_flip);
}

// ---------------- fallback: monolithic kernel (used only if ws too small / A>2^18) ------
__global__ __launch_bounds__(256) void rpn_fused(
    const float4* __restrict__ anchors, const int* __restrict__ valid,
    const int* __restrict__ cls, const float4* __restrict__ gt,
    const float* __restrict__ stdev, float* __restrict__ out,
    unsigned long long* __restrict__ gkey, unsigned* __restrict__ done,
    int* __restrict__ cnt, int A, int G)
{
    __shared__ float4 s_gt[GMAX];
    __shared__ float s_crowdf[GMAX];
    __shared__ unsigned long long s_key[GMAX];
    __shared__ int s_anycrowd; __shared__ int s_cnt; __shared__ int s_islast;

    const int tid = threadIdx.x;
    if (tid == 0) { s_anycrowd = 0; s_cnt = 0; }
    if (tid < G) {
        s_gt[tid] = gt[tid];
        int c = cls[tid];
        s_crowdf[tid] = (c < 0) ? 1.0f : 0.0f;
        if (c < 0) s_anycrowd = 1;
        s_key[tid] = 0ULL;
    }
    __syncthreads();
    const int any_crowd = s_anycrowd;
    const int ai = blockIdx.x * 256 + tid;
    const bool in_range = (ai < A);
    float4 ab = in_range ? anchors[ai] : make_float4(0.f, 0.f, 1.f, 1.f);
    const bool v = in_range && (valid[ai] != 0);
    const float a_area = (ab.z - ab.x) * (ab.w - ab.y);
    const unsigned lokey = ~(unsigned)ai;

    float best = any_crowd ? -2.0f : -1.0f;
    int bg = 0; float crowd_max = 0.0f;
    unsigned long long ovmask[4];
    #pragma unroll
    for (int w = 0; w < 4; ++w) {
        unsigned long long m = 0ULL;
        #pragma unroll 4
        for (int j = 0; j < 64; ++j) {
            int g = (w << 6) + j;
            if (g >= G) break;
            float iou = iou_of(ab, a_area, s_gt[g]);
            float cf = s_crowdf[g];
            float eff = (any_crowd && cf != 0.0f) ? -1.0f : iou;
            if (eff > best) { best = eff; bg = g; }
            if (any_crowd) crowd_max = fmaxf(crowd_max, iou * cf);
            if (v && (cf == 0.0f) && iou > 0.0f) m |= (1ULL << j);
        }
        ovmask[w] = m;
    }
    #pragma unroll
    for (int w = 0; w < 4; ++w) {
        unsigned long long m = ovmask[w];
        while (m != 0ULL) {
            int j = __builtin_ctzll(m); m &= (m - 1ULL);
            int g = (w << 6) + j;
            float iou = iou_of(ab, a_area, s_gt[g]);
            atomicMax(&s_key[g],
                (((unsigned long long)(__float_as_uint(iou) + 1u)) << 32) | lokey);
        }
    }
    bool no_crowd = any_crowd ? (crowd_max < 0.001f) : true;
    bool pos = (best >= 0.7f);
    bool neg = (best < 0.3f) && no_crowd && !pos;
    unsigned long long pv = __ballot((int)(in_range && pos && v));
    if ((tid & 63) == 0) atomicAdd(&s_cnt, (int)__popcll(pv));
    if (in_range) {
        out[ai] = v ? (pos ? 1.0f : (neg ? -1.0f : 0.0f)) : 0.0f;
        float4 d = make_float4(0.f, 0.f, 0.f, 0.f);
        if (pos && v) d = compute_deltas(ab, s_gt[bg], stdev);
        ((float4*)(out + A))[ai] = d;
    }
    __syncthreads();
    if (tid < G && s_key[tid] != 0ULL) atomicMax(&gkey[tid], s_key[tid]);
    if (tid == 0 && s_cnt > 0) atomicAdd(cnt, s_cnt);
    __threadfence();
    if (tid == 0) {
        unsigned prev = atomicAdd(done, 1u);
        s_islast = (prev == gridDim.x - 1);
        s_cnt = 0;
    }
    __syncthreads();
    if (!s_islast) return;
    __threadfence();
    if (tid < G && s_crowdf[tid] == 0.0f) {
        unsigned long long key = gkey[tid];
        int w;
        if (key != 0ULL) w = (int)(~(unsigned)(key & 0xFFFFFFFFull));
        else { w = 0; for (int i = 0; i < A; ++i) { if (valid[i] != 0) { w = i; break; } } }
        if (valid[w] != 0) {
            float old = atomicExch(out + w, 1.0f);
            if (old != 1.0f) {
                float4 ab2 = anchors[w];
                float a2 = (ab2.z - ab2.x) * (ab2.w - ab2.y);
                float b2 = -2.0f; int g2 = 0;
                for (int g = 0; g < G; ++g) {
                    float iou = iou_of(ab2, a2, s_gt[g]);
                    float eff = (s_crowdf[g] != 0.0f) ? -1.0f : iou;
                    if (eff > b2) { b2 = eff; g2 = g; }
                }
                ((float4*)(out + A))[w] = compute_deltas(ab2, s_gt[g2], stdev);
                atomicAdd(&s_cnt, 1);
            }
        }
    }
    __syncthreads();
    if (tid == 0) out[(size_t)5 * A] = (float)(*cnt + s_cnt);
}

extern "C" void kernel_launch(void* const* d_in, const int* in_sizes, int n_in,
                              void* d_out, int out_size, void* d_ws, size_t ws_size,
                              hipStream_t stream) {
    const float4* anchors = (const float4*)d_in[0];
    const int* valid      = (const int*)d_in[1];   // jnp bool -> int32 per element
    const int* cls        = (const int*)d_in[2];
    const float4* gtb     = (const float4*)d_in[3];
    const float* stdev    = (const float*)d_in[4];
    float* out            = (float*)d_out;

    const int A = in_sizes[0] / 4;
    const int G = in_sizes[2];                     // 256
    const int nb4 = (A + 255) / 256;               // 1023 blocks (256 anchors/block)

    const size_t shard_bytes = (size_t)G * SHARDS * 8;
    const size_t pcnt_bytes  = (size_t)nb4 * 4;
    const size_t fv_bytes    = (size_t)nb4 * 4;
    const size_t needed = shard_bytes + pcnt_bytes + fv_bytes;

    if (ws_size >= needed && G <= GMAX && A <= (1 << 18)) {
        char* p = (char*)d_ws;
        unsigned long long* gkeyS = (unsigned long long*)p;          p += shard_bytes;
        int* pcount               = (int*)p;                         p += pcnt_bytes;
        int* fvmin                = (int*)p;

        rpn_main8<<<nb4, 256, 0, stream>>>(anchors, valid, cls, gtb, stdev, out,
                                           gkeyS, pcount, fvmin, A, G);
        rpn_finalize3<<<1, 1024, 0, stream>>>(anchors, cls, gtb, stdev, out,
                                              gkeyS, pcount, fvmin, nb4, A, G);
    } else {
        const int nb = (A + 255) / 256;
        unsigned long long* gkey = (unsigned long long*)d_ws;
        unsigned* done = (unsigned*)((char*)d_ws + 2048);
        int* cnt       = (int*)((char*)d_ws + 2052);
        hipMemsetAsync(d_ws, 0, 2056, stream);
        rpn_fused<<<nb, 256, 0, stream>>>(anchors, valid, cls, gtb, stdev, out,
                                          gkey, done, cnt, A, G);
    }
}